// Round 7
// baseline (487.141 us; speedup 1.0000x reference)
//
#include <hip/hip_runtime.h>
#include <hip/hip_fp16.h>
#include <math.h>

#define NOBJ  2048
#define EMBED 256
#define NHD   8     // heads
#define NPT   32    // points
#define HD    32    // head dim
#define NUMIMG 4
#define HH    160
#define WW    160
#define FFN   1024
#define PLANE (HH*WW)   // 25600
#define LN_EPS 1e-5f

typedef _Float16 f16x8 __attribute__((ext_vector_type(8)));
typedef float f32x4 __attribute__((ext_vector_type(4)));

// ---------------------------------------------------------------------------
// K-prep: blocks [0,256) = offsets GEMV; blocks [256,832) = weight transposes.
// ---------------------------------------------------------------------------
__global__ __launch_bounds__(256) void k_prep(
    const float* __restrict__ obj_emb, const float* __restrict__ w_off,
    const float* __restrict__ b_off, const float* __restrict__ obj_xy,
    const float* __restrict__ strides,
    float* __restrict__ cx, float* __restrict__ cy,
    const float* __restrict__ w_out, const float* __restrict__ w1,
    const float* __restrict__ w2, _Float16* __restrict__ woT,
    _Float16* __restrict__ w1T, _Float16* __restrict__ w2T) {
  __shared__ float s_emb[8][EMBED];   // offsets branch
  __shared__ float s_t[32][33];       // cvtw branch
  const int t = threadIdx.x;
  if (blockIdx.x < 256) {
    const int G = 8;
    const int n0 = blockIdx.x * G;
    #pragma unroll
    for (int g = 0; g < G; ++g) s_emb[g][t] = obj_emb[(n0 + g) * EMBED + t];
    __syncthreads();
    float ax[G], ay[G];
    #pragma unroll
    for (int g = 0; g < G; ++g) { ax[g] = 0.f; ay[g] = 0.f; }
    const float2* wp = (const float2*)w_off;  // row = 256 float2
    for (int e = 0; e < EMBED; ++e) {
      float2 w = wp[e * 256 + t];
      #pragma unroll
      for (int g = 0; g < G; ++g) {
        float a = s_emb[g][e];
        ax[g] = fmaf(a, w.x, ax[g]);
        ay[g] = fmaf(a, w.y, ay[g]);
      }
    }
    const float bx = b_off[2 * t], by = b_off[2 * t + 1];
    #pragma unroll
    for (int g = 0; g < G; ++g) {
      const int n = n0 + g;
      const float st = strides[n];
      const float lx = obj_xy[2 * n]     + (ax[g] + bx) * st;
      const float ly = obj_xy[2 * n + 1] + (ay[g] + by) * st;
      const float gx = lx * (2.0f / (WW * 4)) - 1.0f;
      const float gy = ly * (2.0f / (HH * 4)) - 1.0f;
      cx[n * 256 + t] = ((gx + 1.0f) * WW - 1.0f) * 0.5f;
      cy[n * 256 + t] = ((gy + 1.0f) * HH - 1.0f) * 0.5f;
    }
  } else {
    const int id = blockIdx.x - 256;
    const float* w; _Float16* wT; int K, N, kt, nt;
    if (id < 64)       { w = w_out; wT = woT; K = 256;  N = 256;
                         kt = id & 7;  nt = id >> 3; }
    else if (id < 320) { const int r = id - 64;  w = w1; wT = w1T;
                         K = 256;  N = 1024; kt = r & 7;  nt = r >> 3; }
    else               { const int r = id - 320; w = w2; wT = w2T;
                         K = 1024; N = 256;  kt = r & 31; nt = r >> 5; }
    const int k0 = kt * 32, n0 = nt * 32;
    const int nl = t & 31, kg = t >> 5;
    #pragma unroll
    for (int i = 0; i < 4; ++i) {
      const int k = kg * 4 + i;
      s_t[k][nl] = w[(size_t)(k0 + k) * N + n0 + nl];
    }
    __syncthreads();
    const int kl = t & 31, ng = t >> 5;
    #pragma unroll
    for (int i = 0; i < 4; ++i) {
      const int n = ng * 4 + i;
      wT[(size_t)(n0 + n) * K + k0 + kl] = (_Float16)s_t[kl][n];
    }
  }
}

// ---------------------------------------------------------------------------
// K-relayout v4 (2.1 TB/s wall across 4 structural variants), split in halves.
// key_feat/value (img,c,y,x) f32 -> kvh (img,y,x,h,kv,c) f16.
// ---------------------------------------------------------------------------
__global__ __launch_bounds__(512) void k_relayout(
    const float* __restrict__ key_feat, const float* __restrict__ value,
    __half* __restrict__ kvh, int img_base) {
  __shared__ __half s[320][144];  // row stride 288 B
  const int t = threadIdx.x;
  const int Y   = blockIdx.x;              // 0..79  y-pair
  const int hp  = blockIdx.y;              // 0..3   head pair
  const int img = img_base + blockIdx.z;   // 2 images per launch
  const int pl  = t >> 2;
  const int q   = t & 3;

  const int sub  = pl & 31;
  const int grp  = pl >> 5;
  const int head = hp * 2 + (grp >> 1);
  const int ch   = head * 32 + sub;
  const float* src = (grp & 1) ? value : key_feat;
  const float* sp  = src + ((size_t)img * 256 + ch) * PLANE
                   + (size_t)Y * 320 + q * 80;
  const int pxq = q * 80;

  #pragma unroll
  for (int i0 = 0; i0 < 20; i0 += 10) {
    float4 r[10];
    #pragma unroll
    for (int i = 0; i < 10; ++i) r[i] = *(const float4*)(sp + (i0 + i) * 4);
    #pragma unroll
    for (int i = 0; i < 10; ++i) {
      const int px = pxq + (i0 + i) * 4;
      s[px + 0][pl] = __float2half(r[i].x);
      s[px + 1][pl] = __float2half(r[i].y);
      s[px + 2][pl] = __float2half(r[i].z);
      s[px + 3][pl] = __float2half(r[i].w);
    }
  }
  __syncthreads();

  const size_t rec = (size_t)img * PLANE + (size_t)Y * 320;
  #pragma unroll
  for (int it = 0; it < 10; ++it) {
    const int flat = it * 512 + t;
    const int px = flat >> 4, j = flat & 15;
    const int4 v = *(const int4*)&s[px][j * 8];
    *(int4*)(kvh + (rec + px) * 512 + hp * 128 + j * 8) = v;
  }
}

// ---------------------------------------------------------------------------
__device__ __forceinline__ void acc8(int4 r, float w, float* acc) {
  const __half2* hp = (const __half2*)&r;
  #pragma unroll
  for (int i = 0; i < 4; ++i) {
    const float2 f = __half22float2(hp[i]);
    acc[2 * i]     = fmaf(w, f.x, acc[2 * i]);
    acc[2 * i + 1] = fmaf(w, f.y, acc[2 * i + 1]);
  }
}

// ---------------------------------------------------------------------------
// K2: sample. LDS diet: s_v in f16 (19.5 KB total) -> 8 blocks/CU target.
// ---------------------------------------------------------------------------
__global__ __launch_bounds__(256) void k_sample_hwc(
    const float* __restrict__ query, const __half* __restrict__ kvh,
    const float* __restrict__ x2d, const float* __restrict__ x2d_mask,
    const int* __restrict__ obj_img,
    const float* __restrict__ cx, const float* __restrict__ cy,
    float* __restrict__ o_vs, float* __restrict__ o_as,
    float* __restrict__ o_ms, float* __restrict__ o_x2,
    _Float16* __restrict__ attn_h) {
  __shared__ float s_q[256];
  __shared__ _Float16 s_v[NHD * NPT * 34];
  __shared__ float s_asm[256];

  const int n = blockIdx.x;
  const int t = threadIdx.x;
  const int h = t >> 5, p = t & 31;

  s_q[t] = query[n * 256 + t];
  const int img = obj_img[n];
  const float ix = cx[n * 256 + t];
  const float iy = cy[n * 256 + t];

  const float x0f = floorf(ix), y0f = floorf(iy);
  const float wx1 = ix - x0f, wy1 = iy - y0f;
  const int x0 = (int)x0f, y0 = (int)y0f;
  const int x1 = x0 + 1, y1 = y0 + 1;
  const int x0c = min(max(x0, 0), WW - 1), x1c = min(max(x1, 0), WW - 1);
  const int y0c = min(max(y0, 0), HH - 1), y1c = min(max(y1, 0), HH - 1);
  const float w00 = (1.f - wx1) * (1.f - wy1);
  const float w10 = wx1 * (1.f - wy1);
  const float w01 = (1.f - wx1) * wy1;
  const float w11 = wx1 * wy1;
  const int o00 = y0c * WW + x0c, o10 = y0c * WW + x1c;
  const int o01 = y1c * WW + x0c, o11 = y1c * WW + x1c;

  const size_t pb = (size_t)img * PLANE;
  const int4* base = (const int4*)kvh;
  const long b0 = ((long)(pb + o00)) * 64 + h * 8;
  const long b1 = ((long)(pb + o10)) * 64 + h * 8;
  const long b2 = ((long)(pb + o01)) * 64 + h * 8;
  const long b3 = ((long)(pb + o11)) * 64 + h * 8;
  __syncthreads();

  float a_acc = 0.f;
  _Float16* svrow = &s_v[(h * NPT + p) * 34];
  float* vout = o_vs + (size_t)(n * NHD + h) * (HD * NPT) + p;
  #pragma unroll
  for (int ch = 0; ch < 4; ++ch) {
    const int4 k0 = base[b0 + ch],     k1 = base[b1 + ch];
    const int4 k2 = base[b2 + ch],     k3 = base[b3 + ch];
    const int4 v0 = base[b0 + 4 + ch], v1 = base[b1 + 4 + ch];
    const int4 v2 = base[b2 + 4 + ch], v3 = base[b3 + 4 + ch];
    float kc[8] = {0, 0, 0, 0, 0, 0, 0, 0};
    float vc[8] = {0, 0, 0, 0, 0, 0, 0, 0};
    acc8(k0, w00, kc); acc8(k1, w10, kc); acc8(k2, w01, kc); acc8(k3, w11, kc);
    acc8(v0, w00, vc); acc8(v1, w10, vc); acc8(v2, w01, vc); acc8(v3, w11, vc);
    #pragma unroll
    for (int j = 0; j < 8; ++j) {
      const int c = ch * 8 + j;
      a_acc = fmaf(s_q[h * HD + c], kc[j], a_acc);
      svrow[c] = (_Float16)vc[j];
      vout[c * NPT] = vc[j];
    }
  }

  const float a = a_acc * 0.17677669529663687f;  // 1/sqrt(32)
  o_as[n * 256 + t] = a;

  const float* xb0 = x2d + (size_t)img * 2 * PLANE;
  const float* xb1 = xb0 + PLANE;
  const float x2v0 = w00 * xb0[o00] + w10 * xb0[o10] + w01 * xb0[o01] + w11 * xb0[o11];
  const float x2v1 = w00 * xb1[o00] + w10 * xb1[o10] + w01 * xb1[o01] + w11 * xb1[o11];
  o_x2[(size_t)n * 512 + h * 64 + p]      = x2v0;
  o_x2[(size_t)n * 512 + h * 64 + 32 + p] = x2v1;

  const float* mb = x2d_mask + (size_t)img * PLANE;
  const float m00 = (x0 >= 0 && x0 < WW && y0 >= 0 && y0 < HH) ? w00 : 0.f;
  const float m10 = (x1 >= 0 && x1 < WW && y0 >= 0 && y0 < HH) ? w10 : 0.f;
  const float m01 = (x0 >= 0 && x0 < WW && y1 >= 0 && y1 < HH) ? w01 : 0.f;
  const float m11 = (x1 >= 0 && x1 < WW && y1 >= 0 && y1 < HH) ? w11 : 0.f;
  const float m = m00 * mb[o00] + m10 * mb[o10] + m01 * mb[o01] + m11 * mb[o11];
  o_ms[n * 256 + t] = m;

  float mx = a;
  #pragma unroll
  for (int o = 16; o >= 1; o >>= 1) mx = fmaxf(mx, __shfl_xor(mx, o, 32));
  const float ev = expf(a - mx);
  float s = ev;
  #pragma unroll
  for (int o = 16; o >= 1; o >>= 1) s += __shfl_xor(s, o, 32);
  s_asm[t] = ev / s * m;
  __syncthreads();

  const int d = p;
  float o = 0.f;
  const _Float16* svh = &s_v[h * NPT * 34];
  const float* amh = &s_asm[h * NPT];
  #pragma unroll
  for (int pp = 0; pp < NPT; ++pp)
    o = fmaf(amh[pp], (float)svh[pp * 34 + d], o);
  attn_h[n * 256 + t] = (_Float16)o;
}

// ---------------------------------------------------------------------------
// K-tail: fused gemm_a+LN1+gemm_b(relu)+gemm_c+LN2. The whole chain is
// row-local -> block owns 16 rows; Uh/U/Fh live in LDS only. 8 waves:
// wave owns an N-slice per stage. MFMA frag maps as in the unfused GEMMs.
// Single-pass LN (E[x^2]-m^2), one LDS partial-reduce per LN.
// ---------------------------------------------------------------------------
__global__ __launch_bounds__(512) void k_tail(
    const _Float16* __restrict__ attn_h, const _Float16* __restrict__ woT,
    const _Float16* __restrict__ w1T, const _Float16* __restrict__ w2T,
    const float* __restrict__ b_out, const float* __restrict__ obj_emb,
    const float* __restrict__ g1, const float* __restrict__ bb1,
    const float* __restrict__ b1, const float* __restrict__ b2,
    const float* __restrict__ g2, const float* __restrict__ bb2,
    float* __restrict__ out) {
  __shared__ _Float16 sUh[16][264];   // 8448 B
  __shared__ float    sU [16][264];   // 16896 B (f32 residual for LN2)
  __shared__ _Float16 sF [16][1032];  // 33024 B
  __shared__ float    sP[8][16];      // per-wave per-row sum
  __shared__ float    sQ[8][16];      // per-wave per-row sumsq
  const int t = threadIdx.x;
  const int wv = t >> 6, lane = t & 63;
  const int r16 = lane & 15, quad = lane >> 4;
  const int m0 = blockIdx.x * 16;

  // ---------------- S1: gemm_a (this wave: cols wv*32 .. +31) --------------
  {
    const int c0 = wv * 32;
    const _Float16* ap  = attn_h + (size_t)(m0 + r16) * 256 + quad * 8;
    const _Float16* bp0 = woT + (size_t)(c0 + r16) * 256 + quad * 8;
    const _Float16* bp1 = bp0 + 16 * 256;
    f32x4 acc0 = {0.f,0.f,0.f,0.f}, acc1 = {0.f,0.f,0.f,0.f};
    #pragma unroll
    for (int kc = 0; kc < 256; kc += 32) {
      f16x8 a  = *(const f16x8*)(ap + kc);
      f16x8 b0 = *(const f16x8*)(bp0 + kc);
      f16x8 b1f = *(const f16x8*)(bp1 + kc);
      acc0 = __builtin_amdgcn_mfma_f32_16x16x32_f16(a, b0, acc0, 0, 0, 0);
      acc1 = __builtin_amdgcn_mfma_f32_16x16x32_f16(a, b1f, acc1, 0, 0, 0);
    }
    const int col0 = c0 + r16, col1 = c0 + 16 + r16;
    const float bo0 = b_out[col0], bo1 = b_out[col1];
    float v0[4], v1[4];
    #pragma unroll
    for (int r = 0; r < 4; ++r) {
      const size_t row = (size_t)(m0 + quad * 4 + r) * 256;
      v0[r] = acc0[r] + bo0 + obj_emb[row + col0];
      v1[r] = acc1[r] + bo1 + obj_emb[row + col1];
    }
    // per-row partials over this wave's 32 cols (reduce across r16)
    #pragma unroll
    for (int r = 0; r < 4; ++r) {
      float s = v0[r] + v1[r];
      float q = v0[r] * v0[r] + v1[r] * v1[r];
      #pragma unroll
      for (int m = 1; m < 16; m <<= 1) {
        s += __shfl_xor(s, m);
        q += __shfl_xor(q, m);
      }
      if (r16 == 0) { sP[wv][quad * 4 + r] = s; sQ[wv][quad * 4 + r] = q; }
    }
    __syncthreads();
    const float g0 = g1[col0], be0 = bb1[col0];
    const float g1v = g1[col1], be1 = bb1[col1];
    #pragma unroll
    for (int r = 0; r < 4; ++r) {
      const int rr = quad * 4 + r;
      float S = 0.f, Q = 0.f;
      #pragma unroll
      for (int w = 0; w < 8; ++w) { S += sP[w][rr]; Q += sQ[w][rr]; }
      const float mean = S * (1.0f / EMBED);
      const float var  = Q * (1.0f / EMBED) - mean * mean;
      const float rstd = rsqrtf(var + LN_EPS);
      const float u0 = (v0[r] - mean) * rstd * g0 + be0;
      const float u1 = (v1[r] - mean) * rstd * g1v + be1;
      sU[rr][col0] = u0;  sUh[rr][col0] = (_Float16)u0;
      sU[rr][col1] = u1;  sUh[rr][col1] = (_Float16)u1;
    }
  }
  __syncthreads();

  // ---------------- S2: gemm_b (this wave: cols wv*128 .. +127), relu ------
  {
    const int c0 = wv * 128;
    f32x4 acc[8];
    #pragma unroll
    for (int i = 0; i < 8; ++i) acc[i] = (f32x4){0.f,0.f,0.f,0.f};
    for (int kc = 0; kc < 256; kc += 32) {
      f16x8 a = *(const f16x8*)&sUh[r16][quad * 8 + kc];
      #pragma unroll
      for (int nt = 0; nt < 8; ++nt) {
        f16x8 b = *(const f16x8*)(w1T + (size_t)(c0 + nt * 16 + r16) * 256
                                  + quad * 8 + kc);
        acc[nt] = __builtin_amdgcn_mfma_f32_16x16x32_f16(a, b, acc[nt], 0, 0, 0);
      }
    }
    #pragma unroll
    for (int nt = 0; nt < 8; ++nt) {
      const int col = c0 + nt * 16 + r16;
      const float bb = b1[col];
      #pragma unroll
      for (int r = 0; r < 4; ++r)
        sF[quad * 4 + r][col] = (_Float16)fmaxf(acc[nt][r] + bb, 0.f);
    }
  }
  __syncthreads();

  // ---------------- S3: gemm_c (this wave: cols wv*32 .. +31) + LN2 --------
  {
    const int c0 = wv * 32;
    const _Float16* bp0 = w2T + (size_t)(c0 + r16) * 1024 + quad * 8;
    const _Float16* bp1 = bp0 + 16 * 1024;
    f32x4 acc0 = {0.f,0.f,0.f,0.f}, acc1 = {0.f,0.f,0.f,0.f};
    for (int kc = 0; kc < 1024; kc += 32) {
      f16x8 a  = *(const f16x8*)&sF[r16][quad * 8 + kc];
      f16x8 b0 = *(const f16x8*)(bp0 + kc);
      f16x8 b1f = *(const f16x8*)(bp1 + kc);
      acc0 = __builtin_amdgcn_mfma_f32_16x16x32_f16(a, b0, acc0, 0, 0, 0);
      acc1 = __builtin_amdgcn_mfma_f32_16x16x32_f16(a, b1f, acc1, 0, 0, 0);
    }
    const int col0 = c0 + r16, col1 = c0 + 16 + r16;
    const float bo0 = b2[col0], bo1 = b2[col1];
    float v0[4], v1[4];
    #pragma unroll
    for (int r = 0; r < 4; ++r) {
      const int rr = quad * 4 + r;
      v0[r] = acc0[r] + bo0 + sU[rr][col0];
      v1[r] = acc1[r] + bo1 + sU[rr][col1];
    }
    #pragma unroll
    for (int r = 0; r < 4; ++r) {
      float s = v0[r] + v1[r];
      float q = v0[r] * v0[r] + v1[r] * v1[r];
      #pragma unroll
      for (int m = 1; m < 16; m <<= 1) {
        s += __shfl_xor(s, m);
        q += __shfl_xor(q, m);
      }
      if (r16 == 0) { sP[wv][quad * 4 + r] = s; sQ[wv][quad * 4 + r] = q; }
    }
    __syncthreads();
    const float g0 = g2[col0], be0 = bb2[col0];
    const float g1v = g2[col1], be1 = bb2[col1];
    #pragma unroll
    for (int r = 0; r < 4; ++r) {
      const int rr = quad * 4 + r;
      float S = 0.f, Q = 0.f;
      #pragma unroll
      for (int w = 0; w < 8; ++w) { S += sP[w][rr]; Q += sQ[w][rr]; }
      const float mean = S * (1.0f / EMBED);
      const float var  = Q * (1.0f / EMBED) - mean * mean;
      const float rstd = rsqrtf(var + LN_EPS);
      const size_t row = (size_t)(m0 + rr) * 256;
      out[row + col0] = (v0[r] - mean) * rstd * g0 + be0;
      out[row + col1] = (v1[r] - mean) * rstd * g1v + be1;
    }
  }
}

// ---------------------------------------------------------------------------
extern "C" void kernel_launch(void* const* d_in, const int* in_sizes, int n_in,
                              void* d_out, int out_size, void* d_ws, size_t ws_size,
                              hipStream_t stream) {
  const float* query    = (const float*)d_in[0];
  const float* obj_emb  = (const float*)d_in[1];
  const float* key_feat = (const float*)d_in[2];
  const float* value    = (const float*)d_in[3];
  const float* x2d      = (const float*)d_in[4];
  const float* x2d_mask = (const float*)d_in[5];
  const float* obj_xy   = (const float*)d_in[6];
  const float* strides  = (const float*)d_in[7];
  const int*   obj_img  = (const int*)d_in[8];
  const float* w_off    = (const float*)d_in[9];
  const float* b_off    = (const float*)d_in[10];
  const float* w_out    = (const float*)d_in[11];
  const float* b_out    = (const float*)d_in[12];
  const float* ln1_g    = (const float*)d_in[13];
  const float* ln1_b    = (const float*)d_in[14];
  const float* w1       = (const float*)d_in[15];
  const float* b1       = (const float*)d_in[16];
  const float* w2       = (const float*)d_in[17];
  const float* b2       = (const float*)d_in[18];
  const float* ln2_g    = (const float*)d_in[19];
  const float* ln2_b    = (const float*)d_in[20];

  float* out = (float*)d_out;
  float* o_out = out;
  float* o_vs  = out + 524288;                       // (2048,8,32,32)
  float* o_as  = out + 524288 + 16777216;            // 17301504
  float* o_ms  = out + 524288 + 16777216 + 524288;   // 17825792
  float* o_x2  = out + 524288 + 16777216 + 1048576;  // 18350080

  // workspace: kvh 0..100MB; B = +100MB: cx(2MB) cy(2MB) attn_h(1MB)
  //            woT(128KB) w1T(512KB) w2T(512KB)
  char* wsb = (char*)d_ws;
  __half*    kvh    = (__half*)wsb;
  char* B = wsb + 104857600;
  float*     cx     = (float*)(B);
  float*     cy     = (float*)(B + 2097152);
  _Float16*  attn_h = (_Float16*)(B + 4194304);
  _Float16*  woT    = (_Float16*)(B + 5242880);
  _Float16*  w1T    = (_Float16*)(B + 5242880 + 131072);
  _Float16*  w2T    = (_Float16*)(B + 5242880 + 131072 + 524288);

  k_prep<<<832, 256, 0, stream>>>(obj_emb, w_off, b_off, obj_xy, strides,
                                  cx, cy, w_out, w1, w2, woT, w1T, w2T);
  k_relayout<<<dim3(80, 4, 2), 512, 0, stream>>>(key_feat, value, kvh, 0);
  k_relayout<<<dim3(80, 4, 2), 512, 0, stream>>>(key_feat, value, kvh, 2);
  k_sample_hwc<<<NOBJ, 256, 0, stream>>>(query, kvh, x2d, x2d_mask, obj_img,
                                         cx, cy, o_vs, o_as, o_ms, o_x2,
                                         attn_h);
  k_tail<<<NOBJ / 16, 512, 0, stream>>>(attn_h, woT, w1T, w2T, b_out, obj_emb,
                                        ln1_g, ln1_b, b1, b2, ln2_g, ln2_b,
                                        o_out);
}